// Round 4
// baseline (707.961 us; speedup 1.0000x reference)
//
#include <hip/hip_runtime.h>
#include <hip/hip_bf16.h>
#include <hip/hip_fp16.h>

// Problem dims
#define A_DIM 4608   // C*9 patch-feature rows
#define L_DIM 4096   // (H/3)*(W/3) spatial columns
#define CH    512
#define H_DIM 192
#define W_DIM 192

// GEMM tile (R11: 128x128, BK=16 -> 16 KB/stage, 32 KB/block double-buffered,
// 4 blocks/CU = 4 waves/SIMD. R10 diagnosis: latency/sync-bound at 2 waves/
// SIMD (MFMA pipe 43% busy, LDS port ~35% busy - neither saturated).
#define BM 128
#define BN 128
#define BK 16        // 2 kchunks of 8 halves per stage
#define NS (L_DIM / BK)

#define CPB 32       // prep: channels per block

typedef _Float16 half8 __attribute__((ext_vector_type(8)));
typedef float   floatx4 __attribute__((ext_vector_type(4)));
typedef float   floatx16 __attribute__((ext_vector_type(16)));

// ---------------------------------------------------------------------------
// Pass 1: unfold(x) -> k-chunk-major f16 hi/lo split + global sum-of-squares
// accumulation (ss arrays pre-zeroed). R11: block-local LDS atomic reduction
// replaced by 8-lane shuffle reduce (threads sharing c_l are consecutive
// lanes) + one global atomic per (c_l, q); drops one __syncthreads and all
// LDS atomics.
// Global layout: U[(l>>3)*A_DIM + a][8] (chunk-major; GEMM staging contiguous
// and conflict-free — verified: GEMM SQ_LDS_BANK_CONFLICT = 0).
// ---------------------------------------------------------------------------
__global__ __launch_bounds__(256) void prep_kernel(
    const float* __restrict__ x0, const float* __restrict__ x1,
    _Float16* __restrict__ Uhi0, _Float16* __restrict__ Ulo0,
    _Float16* __restrict__ Uhi1, _Float16* __restrict__ Ulo1,
    float* __restrict__ ss0, float* __restrict__ ss1) {
  const int which = blockIdx.z;
  const float* __restrict__ x = which ? x1 : x0;
  _Float16* __restrict__ Uhi = which ? Uhi1 : Uhi0;
  _Float16* __restrict__ Ulo = which ? Ulo1 : Ulo0;
  float* __restrict__ ssg = which ? ss1 : ss0;

  const int ph = blockIdx.y;            // 0..63
  const int c0 = blockIdx.x * CPB;      // channel group base
  const int abase = blockIdx.x * (CPB * 9);

  __shared__ _Float16 sHi[CPB * 9 * 8 * 8];  // 288 rows x 8 chunks x 8 halves
  __shared__ _Float16 sLo[CPB * 9 * 8 * 8];

  const int t = threadIdx.x;

  // ---- phase 1: read input, assemble 16B chunks in regs, stage in LDS
  const int c_l = t >> 3;               // 0..31
  const int s = t & 7;                  // chunk index this thread owns
  const float* __restrict__ rowbase =
      x + ((size_t)(c0 + c_l) * H_DIM + 3 * ph) * W_DIM + s * 24;
  float ssp[9] = {0.f, 0.f, 0.f, 0.f, 0.f, 0.f, 0.f, 0.f, 0.f};

#pragma unroll
  for (int kh = 0; kh < 3; ++kh) {
    const float* __restrict__ rp = rowbase + kh * W_DIM;
    floatx4 v4[6];
#pragma unroll
    for (int i = 0; i < 6; ++i) v4[i] = *(const floatx4*)(rp + i * 4);
    half8 hv[3], lv[3];
#pragma unroll
    for (int i = 0; i < 6; ++i)
#pragma unroll
      for (int j = 0; j < 4; ++j) {
        const int m = i * 4 + j;        // 0..23
        const int kw = m % 3, e = m / 3;
        const float v = v4[i][j];
        ssp[kh * 3 + kw] += v * v;
        const _Float16 h = (_Float16)v;
        hv[kw][e] = h;
        lv[kw][e] = (_Float16)(v - (float)h);
      }
#pragma unroll
    for (int kw = 0; kw < 3; ++kw) {
      const int a_l = c_l * 9 + kh * 3 + kw;
      const int addr = (a_l * 8 + (s ^ (a_l & 7))) * 8;  // XOR-swizzled chunk
      *(half8*)&sHi[addr] = hv[kw];
      *(half8*)&sLo[addr] = lv[kw];
    }
  }
  // ---- norm accumulation: 8-lane shuffle reduce over s, one global atomic
#pragma unroll
  for (int q = 0; q < 9; ++q) {
    float v = ssp[q];
    v += __shfl_down(v, 4, 8);
    v += __shfl_down(v, 2, 8);
    v += __shfl_down(v, 1, 8);
    if (s == 0) atomicAdd(&ssg[abase + c_l * 9 + q], v);
  }
  __syncthreads();

  // ---- phase 2: coalesced global writes (consecutive t = consecutive a)
#pragma unroll
  for (int i = 0; i < 9; ++i) {
    const int idx = i * 256 + t;        // 0..2303
    const int c8 = idx / 288;
    const int a_l = idx - c8 * 288;
    const int addr = (a_l * 8 + (c8 ^ (a_l & 7))) * 8;
    const size_t g = ((size_t)(ph * 8 + c8) * A_DIM + abase + a_l) * 8;
    *(half8*)&Uhi[g] = *(const half8*)&sHi[addr];
    *(half8*)&Ulo[g] = *(const half8*)&sLo[addr];
  }
}

// ---------------------------------------------------------------------------
// Pass 2: D[i,j] = sty_i . img_j, 3-term f16 split, 32x32x16 MFMA, 128x128
// tile, BK=16, double-buffered LDS with the proven loop order:
//   ISSUE(ks+1) -> s_waitcnt vmcnt(4) [stage ks complete, ks+1 stays in
//   flight across the barrier] -> s_barrier -> compute -> s_barrier.
// (Never cross the barrier with an empty VMEM queue.)
//
// R11: 4 blocks/CU (32 KB LDS each), 4 waves/SIMD. R10 post-mortem showed
// latency/sync-bound: MFMA pipe 43% busy AND LDS port ~35% busy at 2 waves/
// SIMD — the fix is concurrency, not reordering (R3's intra-wave interleave
// regressed). Per-acc MFMA sequence identical to R2 -> bit-identical output.
//
// Block swizzle (1-D grid, 1296 = 4*288 + 144 blocks): id -> (bx,by) such
// that XCD (heuristic id%8) pins one B col-tile across all 36 by-steps.
// ---------------------------------------------------------------------------
#define GLDS(g, l)                                                          \
  __builtin_amdgcn_global_load_lds(                                        \
      (const __attribute__((address_space(1))) void*)(g),                   \
      (__attribute__((address_space(3))) void*)(l), 16, 0, 0)

__global__ __launch_bounds__(256, 4) void gemm_max_kernel(
    const _Float16* __restrict__ Shi, const _Float16* __restrict__ Slo,
    const _Float16* __restrict__ Ihi, const _Float16* __restrict__ Ilo,
    const float* __restrict__ img_ss,
    unsigned long long* __restrict__ packed) {
  // Per-buffer layout (halves): Ah[0,2048) Al[2048,4096) Bh[4096,6144)
  // Bl[6144,8192). 2 kchunks x 128 rows x 8 halves per matrix. 32 KB total.
  __shared__ _Float16 sm[2][8192];

  const int t = threadIdx.x;
  const int lane = t & 63, wv = t >> 6;
  const int wvr = wv >> 1, wvc = wv & 1;       // 2x2 waves, wave tile 64x64
  // swizzled block mapping: groups of 8 columns; within a group, consecutive
  // linear ids step `by` with bx_lo (=XCD slot) fixed.
  const int id = blockIdx.x;
  int bx, by;
  if (id < 1152) {
    const int g = id / 288, r = id - g * 288;
    by = r >> 3; bx = g * 8 + (r & 7);
  } else {
    const int r = id - 1152;
    by = r >> 2; bx = 32 + (r & 3);
  }
  const int row0 = by * BM;                    // sty rows (i)
  const int col0 = bx * BN;                    // img rows (j)
  const int l31 = lane & 31, hs = lane >> 5;

  floatx16 acc[2][2];
#pragma unroll
  for (int rf = 0; rf < 2; ++rf)
#pragma unroll
    for (int cf = 0; cf < 2; ++cf) acc[rf][cf] = (floatx16)0.f;

  // Staging: thread t covers (plane = t>>7, row = t&127); exactly one GLDS
  // per matrix. LDS dest = linear 16B/thread (wave-uniform base + lane*16).
  const size_t CH8 = (size_t)A_DIM * 8;        // one kchunk plane, in halves
  const size_t aOff = (size_t)(t >> 7) * CH8 + (size_t)(row0 + (t & 127)) * 8;
  const size_t bOff = (size_t)(t >> 7) * CH8 + (size_t)(col0 + (t & 127)) * 8;
  const int dl = t * 8;  // halves == t*16 bytes

#define ISSUE(b, koff)                              \
  do {                                              \
    GLDS(Shi + (koff) + aOff, &sm[b][dl]);          \
    GLDS(Slo + (koff) + aOff, &sm[b][2048 + dl]);   \
    GLDS(Ihi + (koff) + bOff, &sm[b][4096 + dl]);   \
    GLDS(Ilo + (koff) + bOff, &sm[b][6144 + dl]);   \
  } while (0)

  ISSUE(0, 0);  // prologue prefetch of stage 0

  for (int ks = 0; ks < NS; ++ks) {
    const int cur = ks & 1;
    if (ks + 1 < NS) {
      ISSUE(1 - cur, (size_t)(ks + 1) * 2 * CH8);
      asm volatile("s_waitcnt vmcnt(4)" ::: "memory");  // stage ks complete
    } else {
      asm volatile("s_waitcnt vmcnt(0)" ::: "memory");
    }
    asm volatile("s_barrier" ::: "memory");  // all waves' stage-ks data in LDS

    const _Float16* __restrict__ S = &sm[cur][0];
    half8 ah[2], al[2], bh[2], bl[2];
#pragma unroll
    for (int rf = 0; rf < 2; ++rf) {
      const int idx = (hs * 128 + wvr * 64 + rf * 32 + l31) * 8;
      ah[rf] = *(const half8*)&S[idx];
      al[rf] = *(const half8*)&S[2048 + idx];
    }
#pragma unroll
    for (int cf = 0; cf < 2; ++cf) {
      const int idx = (hs * 128 + wvc * 64 + cf * 32 + l31) * 8;
      bh[cf] = *(const half8*)&S[4096 + idx];
      bl[cf] = *(const half8*)&S[6144 + idx];
    }
    // term-major order: same acc reused every 4 MFMAs (pipe-latency safe)
#pragma unroll
    for (int rf = 0; rf < 2; ++rf)
#pragma unroll
      for (int cf = 0; cf < 2; ++cf)
        acc[rf][cf] = __builtin_amdgcn_mfma_f32_32x32x16_f16(
            ah[rf], bh[cf], acc[rf][cf], 0, 0, 0);
#pragma unroll
    for (int rf = 0; rf < 2; ++rf)
#pragma unroll
      for (int cf = 0; cf < 2; ++cf)
        acc[rf][cf] = __builtin_amdgcn_mfma_f32_32x32x16_f16(
            ah[rf], bl[cf], acc[rf][cf], 0, 0, 0);
#pragma unroll
    for (int rf = 0; rf < 2; ++rf)
#pragma unroll
      for (int cf = 0; cf < 2; ++cf)
        acc[rf][cf] = __builtin_amdgcn_mfma_f32_32x32x16_f16(
            al[rf], bh[cf], acc[rf][cf], 0, 0, 0);

    asm volatile("s_barrier" ::: "memory");  // reads done before overwrite
  }

  // Epilogue: v[i,j] = rsqrt(img_ss[i]) * D[i,j]; column max+argmax
  // (first-index wins). 32x32 C/D: col=lane&31, row=(reg&3)+8*(reg>>2)+4*hs.
  float nrv[2][16];
#pragma unroll
  for (int rf = 0; rf < 2; ++rf) {
    const int base_i = row0 + wvr * 64 + rf * 32 + 4 * hs;
#pragma unroll
    for (int g2 = 0; g2 < 4; ++g2) {
      const floatx4 s4 = *(const floatx4*)&img_ss[base_i + 8 * g2];
#pragma unroll
      for (int r2 = 0; r2 < 4; ++r2) nrv[rf][g2 * 4 + r2] = 1.0f / sqrtf(s4[r2]);
    }
  }
#pragma unroll
  for (int cf = 0; cf < 2; ++cf) {
    const int j = col0 + wvc * 64 + cf * 32 + l31;
    float best = -3.4e38f;
    int bi = 0x7FFFFFFF;
#pragma unroll
    for (int rf = 0; rf < 2; ++rf) {
      const int base_i = row0 + wvr * 64 + rf * 32 + 4 * hs;
#pragma unroll
      for (int g2 = 0; g2 < 4; ++g2)
#pragma unroll
        for (int r2 = 0; r2 < 4; ++r2) {
          const int i = base_i + 8 * g2 + r2;
          const float v = acc[rf][cf][g2 * 4 + r2] * nrv[rf][g2 * 4 + r2];
          if (v > best) { best = v; bi = i; }  // ascending i => first wins
        }
    }
    const float ov = __shfl_xor(best, 32, 64);
    const int oi = __shfl_xor(bi, 32, 64);
    if (ov > best || (ov == best && oi < bi)) { best = ov; bi = oi; }
    if (hs == 0) {
      const unsigned u = __float_as_uint(best);
      const unsigned key = (u & 0x80000000u) ? ~u : (u | 0x80000000u);
      const unsigned long long pk =
          ((unsigned long long)key << 32) | (unsigned)(~(unsigned)bi);
      atomicMax(&packed[j], pk);
    }
  }
}

// ---------------------------------------------------------------------------
// Pass 3: decode packed, apply rsqrt(sty_ss[j]); out[0..A)=nearest,
// out[A..2A)=max_sim.
// ---------------------------------------------------------------------------
__global__ __launch_bounds__(256) void finalize_kernel(
    const unsigned long long* __restrict__ packed,
    const float* __restrict__ sty_ss, float* __restrict__ out) {
  const int j = blockIdx.x * 256 + threadIdx.x;
  if (j >= A_DIM) return;
  const unsigned long long p = packed[j];
  const unsigned key = (unsigned)(p >> 32);
  const unsigned u = (key & 0x80000000u) ? (key ^ 0x80000000u) : ~key;
  const float v = __uint_as_float(u);
  const int idx = (int)(~(unsigned)(p & 0xFFFFFFFFu));
  out[j] = (float)idx;
  out[A_DIM + j] = v * (1.0f / sqrtf(sty_ss[j]));
}

extern "C" void kernel_launch(void* const* d_in, const int* in_sizes, int n_in,
                              void* d_out, int out_size, void* d_ws, size_t ws_size,
                              hipStream_t stream) {
  const float* model = (const float*)d_in[0];  // img side
  const float* style = (const float*)d_in[1];  // sty side
  float* out = (float*)d_out;
  char* ws = (char*)d_ws;

  const size_t usz = (size_t)A_DIM * L_DIM * 2;  // one f16 matrix: 37,748,736 B
  _Float16* img_hi = (_Float16*)(ws);
  _Float16* img_lo = (_Float16*)(ws + usz);
  _Float16* sty_hi = (_Float16*)(ws + 2 * usz);
  _Float16* sty_lo = (_Float16*)(ws + 3 * usz);
  float* img_ss = (float*)(ws + 4 * usz);        // zeroed accumulators
  float* sty_ss = img_ss + A_DIM;
  unsigned long long* packed = (unsigned long long*)(img_ss + 2 * A_DIM);

  // zero ss accumulators (2*A*4 B) + packed (A*8 B) in one contiguous memset
  hipMemsetAsync(img_ss, 0, (size_t)A_DIM * 16, stream);
  prep_kernel<<<dim3(CH / CPB, H_DIM / 3, 2), 256, 0, stream>>>(
      model, style, img_hi, img_lo, sty_hi, sty_lo, img_ss, sty_ss);
  gemm_max_kernel<<<dim3((A_DIM / BM) * (A_DIM / BN)), 256, 0, stream>>>(
      sty_hi, sty_lo, img_hi, img_lo, img_ss, packed);
  finalize_kernel<<<18, 256, 0, stream>>>(packed, sty_ss, out);
}

// Round 5
// 652.254 us; speedup vs baseline: 1.0854x; 1.0854x over previous
//
#include <hip/hip_runtime.h>
#include <hip/hip_bf16.h>
#include <hip/hip_fp16.h>

// Problem dims
#define A_DIM 4608   // C*9 patch-feature rows
#define L_DIM 4096   // (H/3)*(W/3) spatial columns
#define CH    512
#define H_DIM 192
#define W_DIM 192

// GEMM tile (R2-proven geometry: 128x192, 2x3-frag 64x96 wave tile, 80 KB LDS,
// 2 blocks/CU). R12: 3-phase K-step (T3+T4 port) — see kernel comment.
#define BM 128
#define BN 192
#define BK 32        // 4 kchunks of 8 halves per stage
#define NS (L_DIM / BK)

#define CPB 32       // prep: channels per block

typedef _Float16 half8 __attribute__((ext_vector_type(8)));
typedef float   floatx4 __attribute__((ext_vector_type(4)));
typedef float   floatx16 __attribute__((ext_vector_type(16)));

// ---------------------------------------------------------------------------
// Pass 1: unfold(x) -> k-chunk-major f16 hi/lo split + global sum-of-squares
// accumulation (ss arrays pre-zeroed). 8-lane shuffle reduce + one global
// atomic per (c_l, q).
// Global layout: U[(l>>3)*A_DIM + a][8] (chunk-major; GEMM staging contiguous
// and conflict-free — verified: GEMM SQ_LDS_BANK_CONFLICT = 0).
// ---------------------------------------------------------------------------
__global__ __launch_bounds__(256) void prep_kernel(
    const float* __restrict__ x0, const float* __restrict__ x1,
    _Float16* __restrict__ Uhi0, _Float16* __restrict__ Ulo0,
    _Float16* __restrict__ Uhi1, _Float16* __restrict__ Ulo1,
    float* __restrict__ ss0, float* __restrict__ ss1) {
  const int which = blockIdx.z;
  const float* __restrict__ x = which ? x1 : x0;
  _Float16* __restrict__ Uhi = which ? Uhi1 : Uhi0;
  _Float16* __restrict__ Ulo = which ? Ulo1 : Ulo0;
  float* __restrict__ ssg = which ? ss1 : ss0;

  const int ph = blockIdx.y;            // 0..63
  const int c0 = blockIdx.x * CPB;      // channel group base
  const int abase = blockIdx.x * (CPB * 9);

  __shared__ _Float16 sHi[CPB * 9 * 8 * 8];  // 288 rows x 8 chunks x 8 halves
  __shared__ _Float16 sLo[CPB * 9 * 8 * 8];

  const int t = threadIdx.x;

  // ---- phase 1: read input, assemble 16B chunks in regs, stage in LDS
  const int c_l = t >> 3;               // 0..31
  const int s = t & 7;                  // chunk index this thread owns
  const float* __restrict__ rowbase =
      x + ((size_t)(c0 + c_l) * H_DIM + 3 * ph) * W_DIM + s * 24;
  float ssp[9] = {0.f, 0.f, 0.f, 0.f, 0.f, 0.f, 0.f, 0.f, 0.f};

#pragma unroll
  for (int kh = 0; kh < 3; ++kh) {
    const float* __restrict__ rp = rowbase + kh * W_DIM;
    floatx4 v4[6];
#pragma unroll
    for (int i = 0; i < 6; ++i) v4[i] = *(const floatx4*)(rp + i * 4);
    half8 hv[3], lv[3];
#pragma unroll
    for (int i = 0; i < 6; ++i)
#pragma unroll
      for (int j = 0; j < 4; ++j) {
        const int m = i * 4 + j;        // 0..23
        const int kw = m % 3, e = m / 3;
        const float v = v4[i][j];
        ssp[kh * 3 + kw] += v * v;
        const _Float16 h = (_Float16)v;
        hv[kw][e] = h;
        lv[kw][e] = (_Float16)(v - (float)h);
      }
#pragma unroll
    for (int kw = 0; kw < 3; ++kw) {
      const int a_l = c_l * 9 + kh * 3 + kw;
      const int addr = (a_l * 8 + (s ^ (a_l & 7))) * 8;  // XOR-swizzled chunk
      *(half8*)&sHi[addr] = hv[kw];
      *(half8*)&sLo[addr] = lv[kw];
    }
  }
  // ---- norm accumulation: 8-lane shuffle reduce over s, one global atomic
#pragma unroll
  for (int q = 0; q < 9; ++q) {
    float v = ssp[q];
    v += __shfl_down(v, 4, 8);
    v += __shfl_down(v, 2, 8);
    v += __shfl_down(v, 1, 8);
    if (s == 0) atomicAdd(&ssg[abase + c_l * 9 + q], v);
  }
  __syncthreads();

  // ---- phase 2: coalesced global writes (consecutive t = consecutive a)
#pragma unroll
  for (int i = 0; i < 9; ++i) {
    const int idx = i * 256 + t;        // 0..2303
    const int c8 = idx / 288;
    const int a_l = idx - c8 * 288;
    const int addr = (a_l * 8 + (c8 ^ (a_l & 7))) * 8;
    const size_t g = ((size_t)(ph * 8 + c8) * A_DIM + abase + a_l) * 8;
    *(half8*)&Uhi[g] = *(const half8*)&sHi[addr];
    *(half8*)&Ulo[g] = *(const half8*)&sLo[addr];
  }
}

// ---------------------------------------------------------------------------
// Pass 2: D[i,j] = sty_i . img_j, 3-term f16 split, 32x32x16 MFMA, 128x192
// tile, double-buffered LDS.
//
// R12 (T3+T4 port): all prior 2-barrier-per-K-step schedules plateau at
// 49-53% MfmaUtil regardless of tile (128², 128x192) or occupancy (2 or 4
// blocks/CU) — the m97-structure ceiling. This version splits each K-step
// into 3 phases (one per cf-column, 12 MFMAs each):
//   [G_A(4) for ks+1][vmcnt(4): stage ks mine done][barrier: everyone's done]
//   P0: [reads A kk0+kk1 (8) + B cf0 (4)][G_BH(3)][barrier][lgkm0][12 MFMA][barrier]
//   P1: [reads B cf1 (4)][G_BL(3)][barrier][lgkm0][12 MFMA][barrier]
//   P2: [reads B cf2 (4)][barrier][lgkm0][12 MFMA][barrier]
// Counted vmcnt: 4 new A-loads issued BEFORE the wait so vmcnt(4) waits
// exactly for the previous stage's 10 loads; the VMEM queue never drains
// in the main loop (only at the peeled last step). sched_barrier(0) fences
// keep hipcc from sinking register-only MFMAs across phase barriers.
// Per-acc-element MFMA order: kc=hs {bh,bl,al*bh}, kc=2+hs {bh,bl,al*bh} —
// identical to R2 -> bit-identical output.
//
// Block swizzle (1-D grid, 864 = 3*288 blocks): id -> (bx,by) such that XCD
// (heuristic id%8) pins one B col-tile (3 MB, fits 4 MB XCD-L2) across all
// 36 by-steps.
// ---------------------------------------------------------------------------
#define GLDS(g, l)                                                          \
  __builtin_amdgcn_global_load_lds(                                        \
      (const __attribute__((address_space(1))) void*)(g),                   \
      (__attribute__((address_space(3))) void*)(l), 16, 0, 0)

#define MFMA_(A, B, C) __builtin_amdgcn_mfma_f32_32x32x16_f16(A, B, C, 0, 0, 0)

__global__ __launch_bounds__(256, 2) void gemm_max_kernel(
    const _Float16* __restrict__ Shi, const _Float16* __restrict__ Slo,
    const _Float16* __restrict__ Ihi, const _Float16* __restrict__ Ilo,
    const float* __restrict__ img_ss,
    unsigned long long* __restrict__ packed) {
  // Per-buffer layout (halves): Ah[0,4096) Al[4096,8192) Bh[8192,14336)
  // Bl[14336,20480). 4 kchunks x {128 A rows | 192 B rows} x 8 halves. 80 KB.
  __shared__ _Float16 sm[2][20480];

  const int t = threadIdx.x;
  const int lane = t & 63, wv = t >> 6;
  const int wvr = wv >> 1, wvc = wv & 1;       // 2x2 waves, wave tile 64x96
  const int id = blockIdx.x;
  const int g = id / 288, r = id - g * 288;
  const int by = r >> 3, bx = g * 8 + (r & 7);
  const int row0 = by * BM;                    // sty rows (i)
  const int col0 = bx * BN;                    // img rows (j)
  const int l31 = lane & 31, hs = lane >> 5;

  floatx16 acc[2][3];
#pragma unroll
  for (int rf = 0; rf < 2; ++rf)
#pragma unroll
    for (int cf = 0; cf < 3; ++cf) acc[rf][cf] = (floatx16)0.f;

  // Staging. A: thread t covers (plane = t>>7, row = t&127); two GLDS per
  // matrix (planes +0, +2). B: 3 chunks c = i*256+t, (kc = c/192, row = c%192)
  // precomputed. LDS dest = linear 16B/thread (wave-uniform base + lane*16).
  const size_t CH8 = (size_t)A_DIM * 8;        // one kchunk plane, in halves
  const size_t aOff = (size_t)(t >> 7) * CH8 + (size_t)(row0 + (t & 127)) * 8;
  size_t bOff[3];
#pragma unroll
  for (int i = 0; i < 3; ++i) {
    const int c = i * 256 + t;                 // 0..767
    const int kc = c / 192, rw = c - kc * 192;
    bOff[i] = (size_t)kc * CH8 + (size_t)(col0 + rw) * 8;
  }
  const int dl = t * 8;  // halves == t*16 bytes

#define G_A(b, koff)                                               \
  do {                                                             \
    GLDS(Shi + (koff) + aOff,           &sm[b][dl]);               \
    GLDS(Shi + (koff) + aOff + 2 * CH8, &sm[b][dl + 2048]);        \
    GLDS(Slo + (koff) + aOff,           &sm[b][4096 + dl]);        \
    GLDS(Slo + (koff) + aOff + 2 * CH8, &sm[b][4096 + dl + 2048]); \
  } while (0)
#define G_BH(b, koff)                                              \
  do {                                                             \
    GLDS(Ihi + (koff) + bOff[0], &sm[b][8192 + dl]);               \
    GLDS(Ihi + (koff) + bOff[1], &sm[b][8192 + dl + 2048]);        \
    GLDS(Ihi + (koff) + bOff[2], &sm[b][8192 + dl + 4096]);        \
  } while (0)
#define G_BL(b, koff)                                              \
  do {                                                             \
    GLDS(Ilo + (koff) + bOff[0], &sm[b][14336 + dl]);              \
    GLDS(Ilo + (koff) + bOff[1], &sm[b][14336 + dl + 2048]);       \
    GLDS(Ilo + (koff) + bOff[2], &sm[b][14336 + dl + 4096]);       \
  } while (0)

#define BARRIER asm volatile("s_barrier" ::: "memory")
#define LGKM0 asm volatile("s_waitcnt lgkmcnt(0)" ::: "memory")
#define SCHED0 __builtin_amdgcn_sched_barrier(0)

  // 12 MFMAs for one cf column: per acc element order kc=hs {t0,t1,t2},
  // kc=2+hs {t0,t1,t2} — matches R2.
#define MM12(CF, BH0, BL0, BH1, BL1)                      \
  do {                                                    \
    acc[0][CF] = MFMA_(ah0[0], BH0, acc[0][CF]);          \
    acc[1][CF] = MFMA_(ah0[1], BH0, acc[1][CF]);          \
    acc[0][CF] = MFMA_(ah0[0], BL0, acc[0][CF]);          \
    acc[1][CF] = MFMA_(ah0[1], BL0, acc[1][CF]);          \
    acc[0][CF] = MFMA_(al0[0], BH0, acc[0][CF]);          \
    acc[1][CF] = MFMA_(al0[1], BH0, acc[1][CF]);          \
    acc[0][CF] = MFMA_(ah1[0], BH1, acc[0][CF]);          \
    acc[1][CF] = MFMA_(ah1[1], BH1, acc[1][CF]);          \
    acc[0][CF] = MFMA_(ah1[0], BL1, acc[0][CF]);          \
    acc[1][CF] = MFMA_(ah1[1], BL1, acc[1][CF]);          \
    acc[0][CF] = MFMA_(al1[0], BH1, acc[0][CF]);          \
    acc[1][CF] = MFMA_(al1[1], BH1, acc[1][CF]);          \
  } while (0)

  // fragment read bases (halves)
  const int aA = ((hs)*128 + wvr * 64 + l31) * 8;        // kk0 A (rf0)
  const int aB = ((2 + hs) * 128 + wvr * 64 + l31) * 8;  // kk1 A (rf0)
  const int bA = ((hs)*192 + wvc * 96 + l31) * 8;        // kk0 B (cf0)
  const int bB = ((2 + hs) * 192 + wvc * 96 + l31) * 8;  // kk1 B (cf0)

  // prologue: full stage 0 prefetch
  G_A(0, 0);
  G_BH(0, 0);
  G_BL(0, 0);

  auto kstep = [&](int cur, bool pf, size_t koff) {
    const int nxt = cur ^ 1;
    if (pf) {
      G_A(nxt, koff);
      asm volatile("s_waitcnt vmcnt(4)" ::: "memory");  // stage cur complete
    } else {
      asm volatile("s_waitcnt vmcnt(0)" ::: "memory");
    }
    BARRIER;  // all waves' stage-cur data visible

    const _Float16* __restrict__ S = &sm[cur][0];
    half8 ah0[2], al0[2], ah1[2], al1[2];

    // ---- phase 0: A frags (both kchunks) + B cf0
    ah0[0] = *(const half8*)&S[aA];
    ah0[1] = *(const half8*)&S[aA + 256];
    al0[0] = *(const half8*)&S[4096 + aA];
    al0[1] = *(const half8*)&S[4096 + aA + 256];
    ah1[0] = *(const half8*)&S[aB];
    ah1[1] = *(const half8*)&S[aB + 256];
    al1[0] = *(const half8*)&S[4096 + aB];
    al1[1] = *(const half8*)&S[4096 + aB + 256];
    {
      half8 bh0 = *(const half8*)&S[8192 + bA];
      half8 bl0 = *(const half8*)&S[14336 + bA];
      half8 bh1 = *(const half8*)&S[8192 + bB];
      half8 bl1 = *(const half8*)&S[14336 + bB];
      if (pf) G_BH(nxt, koff);
      BARRIER;
      LGKM0;
      SCHED0;
      __builtin_amdgcn_s_setprio(1);
      MM12(0, bh0, bl0, bh1, bl1);
      __builtin_amdgcn_s_setprio(0);
      SCHED0;
      BARRIER;
    }
    // ---- phase 1: B cf1
    {
      half8 bh0 = *(const half8*)&S[8192 + bA + 256];
      half8 bl0 = *(const half8*)&S[14336 + bA + 256];
      half8 bh1 = *(const half8*)&S[8192 + bB + 256];
      half8 bl1 = *(const half8*)&S[14336 + bB + 256];
      if (pf) G_BL(nxt, koff);
      BARRIER;
      LGKM0;
      SCHED0;
      __builtin_amdgcn_s_setprio(1);
      MM12(1, bh0, bl0, bh1, bl1);
      __builtin_amdgcn_s_setprio(0);
      SCHED0;
      BARRIER;
    }
    // ---- phase 2: B cf2
    {
      half8 bh0 = *(const half8*)&S[8192 + bA + 512];
      half8 bl0 = *(const half8*)&S[14336 + bA + 512];
      half8 bh1 = *(const half8*)&S[8192 + bB + 512];
      half8 bl1 = *(const half8*)&S[14336 + bB + 512];
      BARRIER;
      LGKM0;
      SCHED0;
      __builtin_amdgcn_s_setprio(1);
      MM12(2, bh0, bl0, bh1, bl1);
      __builtin_amdgcn_s_setprio(0);
      SCHED0;
      BARRIER;  // all reads of cur done before next iter's GLDS overwrite
    }
  };

  for (int ks = 0; ks < NS - 1; ++ks)
    kstep(ks & 1, true, (size_t)(ks + 1) * 4 * CH8);
  kstep((NS - 1) & 1, false, 0);

  // Epilogue: v[i,j] = rsqrt(img_ss[i]) * D[i,j]; column max+argmax
  // (first-index wins). 32x32 C/D: col=lane&31, row=(reg&3)+8*(reg>>2)+4*hs.
  float nrv[2][16];
#pragma unroll
  for (int rf = 0; rf < 2; ++rf) {
    const int base_i = row0 + wvr * 64 + rf * 32 + 4 * hs;
#pragma unroll
    for (int g2 = 0; g2 < 4; ++g2) {
      const floatx4 s4 = *(const floatx4*)&img_ss[base_i + 8 * g2];
#pragma unroll
      for (int r2 = 0; r2 < 4; ++r2) nrv[rf][g2 * 4 + r2] = 1.0f / sqrtf(s4[r2]);
    }
  }
#pragma unroll
  for (int cf = 0; cf < 3; ++cf) {
    const int j = col0 + wvc * 96 + cf * 32 + l31;
    float best = -3.4e38f;
    int bi = 0x7FFFFFFF;
#pragma unroll
    for (int rf = 0; rf < 2; ++rf) {
      const int base_i = row0 + wvr * 64 + rf * 32 + 4 * hs;
#pragma unroll
      for (int g2 = 0; g2 < 4; ++g2)
#pragma unroll
        for (int r2 = 0; r2 < 4; ++r2) {
          const int i = base_i + 8 * g2 + r2;
          const float v = acc[rf][cf][g2 * 4 + r2] * nrv[rf][g2 * 4 + r2];
          if (v > best) { best = v; bi = i; }  // ascending i => first wins
        }
    }
    const float ov = __shfl_xor(best, 32, 64);
    const int oi = __shfl_xor(bi, 32, 64);
    if (ov > best || (ov == best && oi < bi)) { best = ov; bi = oi; }
    if (hs == 0) {
      const unsigned u = __float_as_uint(best);
      const unsigned key = (u & 0x80000000u) ? ~u : (u | 0x80000000u);
      const unsigned long long pk =
          ((unsigned long long)key << 32) | (unsigned)(~(unsigned)bi);
      atomicMax(&packed[j], pk);
    }
  }
}

// ---------------------------------------------------------------------------
// Pass 3: decode packed, apply rsqrt(sty_ss[j]); out[0..A)=nearest,
// out[A..2A)=max_sim.
// ---------------------------------------------------------------------------
__global__ __launch_bounds__(256) void finalize_kernel(
    const unsigned long long* __restrict__ packed,
    const float* __restrict__ sty_ss, float* __restrict__ out) {
  const int j = blockIdx.x * 256 + threadIdx.x;
  if (j >= A_DIM) return;
  const unsigned long long p = packed[j];
  const unsigned key = (unsigned)(p >> 32);
  const unsigned u = (key & 0x80000000u) ? (key ^ 0x80000000u) : ~key;
  const float v = __uint_as_float(u);
  const int idx = (int)(~(unsigned)(p & 0xFFFFFFFFu));
  out[j] = (float)idx;
  out[A_DIM + j] = v * (1.0f / sqrtf(sty_ss[j]));
}

extern "C" void kernel_launch(void* const* d_in, const int* in_sizes, int n_in,
                              void* d_out, int out_size, void* d_ws, size_t ws_size,
                              hipStream_t stream) {
  const float* model = (const float*)d_in[0];  // img side
  const float* style = (const float*)d_in[1];  // sty side
  float* out = (float*)d_out;
  char* ws = (char*)d_ws;

  const size_t usz = (size_t)A_DIM * L_DIM * 2;  // one f16 matrix: 37,748,736 B
  _Float16* img_hi = (_Float16*)(ws);
  _Float16* img_lo = (_Float16*)(ws + usz);
  _Float16* sty_hi = (_Float16*)(ws + 2 * usz);
  _Float16* sty_lo = (_Float16*)(ws + 3 * usz);
  float* img_ss = (float*)(ws + 4 * usz);        // zeroed accumulators
  float* sty_ss = img_ss + A_DIM;
  unsigned long long* packed = (unsigned long long*)(img_ss + 2 * A_DIM);

  // zero ss accumulators (2*A*4 B) + packed (A*8 B) in one contiguous memset
  hipMemsetAsync(img_ss, 0, (size_t)A_DIM * 16, stream);
  prep_kernel<<<dim3(CH / CPB, H_DIM / 3, 2), 256, 0, stream>>>(
      model, style, img_hi, img_lo, sty_hi, sty_lo, img_ss, sty_ss);
  gemm_max_kernel<<<dim3((A_DIM / BM) * (A_DIM / BN)), 256, 0, stream>>>(
      sty_hi, sty_lo, img_hi, img_lo, img_ss, packed);
  finalize_kernel<<<18, 256, 0, stream>>>(packed, sty_ss, out);
}